// Round 12
// baseline (61.090 us; speedup 1.0000x reference)
//
#include <hip/hip_runtime.h>

#define NH   8
#define SEQ  2048
#define DIM  512
#define EMB  512
#define DH   64
#define HALF 128
#define QTB  64           // queries per block (16 per wave)
#define KW   272          // 16 + 2*HALF
#define SCS  276          // Sc row stride (f32)

typedef __attribute__((ext_vector_type(8))) short short8;
typedef __attribute__((ext_vector_type(4))) float f32x4;

__device__ __forceinline__ unsigned short f2bf(float f) {
    unsigned int u = __float_as_uint(f);
    return (unsigned short)((u + 0x7fffu + ((u >> 16) & 1u)) >> 16);
}

// packed f32x2 -> bf16x2 (RNE)
__device__ __forceinline__ unsigned cvtpk(float lo, float hi) {
    unsigned r;
    asm("v_cvt_pk_bf16_f32 %0, %1, %2" : "=v"(r) : "v"(lo), "v"(hi));
    return r;
}

__device__ __forceinline__ void gload_lds16(const void* g, void* l) {
    __builtin_amdgcn_global_load_lds((__attribute__((address_space(1))) void*)g,
                                     (__attribute__((address_space(3))) void*)l,
                                     16, 0, 0);
}

// qkv projection (unchanged from R11): 128x64 tiles, BK=64, double-buffered.
__global__ __launch_bounds__(256)
void gemm_qkv(const float* __restrict__ A, const float* __restrict__ B,
              const float* __restrict__ bias, unsigned short* __restrict__ qkvh,
              unsigned short* __restrict__ vT) {
    constexpr int BM = 128, BN = 64, BK = 64;
    __shared__ unsigned short As[2][BM * BK];
    __shared__ unsigned short Bs[2][BN * BK];
    const int bid = blockIdx.x;
    const int wg = (bid & 7) * 96 + (bid >> 3);     // XCD-local A panels
    const int bm = (wg / 24) * BM, bn = (wg % 24) * BN;
    const int t = threadIdx.x, lane = t & 63, wid = t >> 6;
    const int wr = wid >> 1, wc = wid & 1;
    const int lr = lane & 15, lg = lane >> 4;

    f32x4 acc[4][2];
    #pragma unroll
    for (int m = 0; m < 4; ++m)
        #pragma unroll
        for (int n = 0; n < 2; ++n)
            acc[m][n] = (f32x4){0.f, 0.f, 0.f, 0.f};

    float4 rA[4][2], rB[2][2];
    auto loadA = [&](int kt) {
        #pragma unroll
        for (int i = 0; i < 4; ++i) {
            const int c = t + 256 * i, r = c >> 3, c8 = c & 7;
            const float4* s = (const float4*)(A + (size_t)(bm + r) * DIM + kt + c8 * 8);
            rA[i][0] = s[0]; rA[i][1] = s[1];
        }
    };
    auto loadB = [&](int kt) {
        #pragma unroll
        for (int i = 0; i < 2; ++i) {
            const int c = t + 256 * i, r = c >> 3, c8 = c & 7;
            const float4* s = (const float4*)(B + (size_t)(bn + r) * DIM + kt + c8 * 8);
            rB[i][0] = s[0]; rB[i][1] = s[1];
        }
    };

    loadA(0); loadB(0);
    for (int it = 0; it < 8; ++it) {
        const int cur = it & 1;
        #pragma unroll
        for (int i = 0; i < 4; ++i) {
            const int c = t + 256 * i, r = c >> 3, c8 = c & 7;
            const uint4 pk = make_uint4(cvtpk(rA[i][0].x, rA[i][0].y), cvtpk(rA[i][0].z, rA[i][0].w),
                                        cvtpk(rA[i][1].x, rA[i][1].y), cvtpk(rA[i][1].z, rA[i][1].w));
            *(uint4*)&As[cur][r * 64 + ((c8 ^ (r & 7)) << 3)] = pk;
        }
        #pragma unroll
        for (int i = 0; i < 2; ++i) {
            const int c = t + 256 * i, r = c >> 3, c8 = c & 7;
            const uint4 pk = make_uint4(cvtpk(rB[i][0].x, rB[i][0].y), cvtpk(rB[i][0].z, rB[i][0].w),
                                        cvtpk(rB[i][1].x, rB[i][1].y), cvtpk(rB[i][1].z, rB[i][1].w));
            *(uint4*)&Bs[cur][r * 64 + ((c8 ^ (r & 7)) << 3)] = pk;
        }
        __syncthreads();
        if (it < 7) { loadA((it + 1) * BK); loadB((it + 1) * BK); }

        short8 af[2][4], bf[2][2];
        #pragma unroll
        for (int kk = 0; kk < 2; ++kk) {
            #pragma unroll
            for (int m = 0; m < 4; ++m) {
                const int row = wr * 64 + m * 16 + lr;
                af[kk][m] = *(const short8*)&As[cur][row * 64 + (((kk * 4 + lg) ^ (row & 7)) << 3)];
            }
            #pragma unroll
            for (int n = 0; n < 2; ++n) {
                const int row = wc * 32 + n * 16 + lr;
                bf[kk][n] = *(const short8*)&Bs[cur][row * 64 + (((kk * 4 + lg) ^ (row & 7)) << 3)];
            }
        }
        #pragma unroll
        for (int kk = 0; kk < 2; ++kk)
            #pragma unroll
            for (int m = 0; m < 4; ++m)
                #pragma unroll
                for (int n = 0; n < 2; ++n)
                    acc[m][n] = __builtin_amdgcn_mfma_f32_16x16x32_bf16(af[kk][m], bf[kk][n], acc[m][n], 0, 0, 0);
    }
    __syncthreads();

    unsigned short* Tr = &As[0][0];
    #pragma unroll
    for (int n = 0; n < 2; ++n) {
        const int cl = wc * 32 + n * 16 + lr;
        const float bv = bias[bn + cl];
        #pragma unroll
        for (int m = 0; m < 4; ++m)
            #pragma unroll
            for (int r = 0; r < 4; ++r)
                Tr[(wr * 64 + m * 16 + lg * 4 + r) * 72 + cl] = f2bf(acc[m][n][r] + bv);
    }
    __syncthreads();

    const int h = bn / 192, ty = (bn >> 6) % 3;
    const int bb = bm >> 11, s0 = bm & 2047;
    if (ty < 2) {   // Q,K: contiguous [s][d] rows
        unsigned short* plane = qkvh + (((size_t)(bb * NH + h) * 3 + ty) * SEQ) * DH;
        const int s = t >> 1, hf = (t & 1) * 32;
        unsigned short* dst = plane + (size_t)(s0 + s) * DH + hf;
        #pragma unroll
        for (int k8 = 0; k8 < 4; ++k8)
            *(short8*)&dst[k8 * 8] = *(const short8*)&Tr[s * 72 + hf + k8 * 8];
    } else {        // V: transposed packed [d][s] stores
        const int d = t >> 2, pp = t & 3;
        unsigned short* vrow = vT + ((size_t)(bb * NH + h) * DH + d) * SEQ + s0 + pp * 32;
        #pragma unroll
        for (int k8 = 0; k8 < 4; ++k8) {
            alignas(16) unsigned short tmp[8];
            #pragma unroll
            for (int k = 0; k < 8; ++k) tmp[k] = Tr[(pp * 32 + k8 * 8 + k) * 72 + d];
            *(short8*)&vrow[k8 * 8] = *(short8*)tmp;
        }
    }
}

// Windowed attention, barrier-free: block = (b,h, 64-query tile), 4 waves,
// each wave owns a private 16-query sub-tile + private Sc slice. All K/V/Q
// fragment loads direct from global (L2-resident). 512 blocks, XCD-swizzled.
__global__ __launch_bounds__(256)
void attn_mfma(const unsigned short* __restrict__ qkvh,
               const unsigned short* __restrict__ vT,
               const int* __restrict__ pad,
               unsigned short* __restrict__ Yb) {
    const int bid = blockIdx.x;
    const int wg = (bid & 7) * 64 + (bid >> 3);      // XCD-local K/V planes
    const int bh = wg >> 5, qt = wg & 31;
    const int b = bh >> 3, h = bh & 7;
    const int t = threadIdx.x, lane = t & 63, w = t >> 6;
    const int lr = lane & 15, lg = lane >> 4;
    const int i0 = qt * QTB + w * 16;                // wave's query base
    const int kb = i0 - HALF;

    __shared__ float ScAll[4][16 * SCS];             // private per wave
    float* Sc = ScAll[w];

    const unsigned short* Qg = qkvh + ((size_t)bh * 3 + 0) * SEQ * DH;
    const unsigned short* Kg = qkvh + ((size_t)bh * 3 + 1) * SEQ * DH;
    const unsigned short* vTg = vT + (size_t)bh * DH * SEQ;
    const int* padb = pad + b * SEQ;

    // Q fragments straight from global
    short8 qf[2];
    #pragma unroll
    for (int kk = 0; kk < 2; ++kk)
        qf[kk] = *(const short8*)&Qg[(size_t)(i0 + lr) * DH + kk * 32 + lg * 8];

    // ---- scores: 17 key-tiles of 16, no inter-wave deps ----
    #pragma unroll
    for (int jt = 0; jt < 17; ++jt) {
        const int jl = jt * 16 + lr;
        const int j = kb + jl;
        const int jc = j < 0 ? 0 : (j > SEQ - 1 ? SEQ - 1 : j);
        const int kv = (j >= 0 && j < SEQ) ? padb[j] : 0;
        f32x4 a0 = (f32x4){0.f, 0.f, 0.f, 0.f};
        #pragma unroll
        for (int kk = 0; kk < 2; ++kk) {
            const short8 bfr = *(const short8*)&Kg[(size_t)jc * DH + kk * 32 + lg * 8];
            a0 = __builtin_amdgcn_mfma_f32_16x16x32_bf16(qf[kk], bfr, a0, 0, 0, 0);
        }
        #pragma unroll
        for (int r = 0; r < 4; ++r) {
            const int q0 = lg * 4 + r;
            const bool ok = kv && (jl >= q0) && (jl <= q0 + 2 * HALF);
            Sc[q0 * SCS + jl] = ok ? a0[r] * 0.125f : -1e30f;
        }
    }
    asm volatile("" ::: "memory");

    // ---- softmax: 16 rows serially, full wave per row; bf16 P in place ----
    for (int r = 0; r < 16; ++r) {
        float* row = &Sc[r * SCS];
        unsigned short* prow = (unsigned short*)row;
        if (!padb[i0 + r]) {
            #pragma unroll
            for (int u = 0; u < 5; ++u) {
                const int jl = lane + 64 * u;
                if (jl < KW) prow[jl] = 0;
            }
            if (lane >= 16 && lane < 32) prow[256 + lane] = 0;   // pad 272..287
            continue;
        }
        float v[5];
        float mx = -1e30f;
        #pragma unroll
        for (int u = 0; u < 5; ++u) {
            const int jl = lane + 64 * u;
            v[u] = (jl < KW) ? row[jl] : -1e30f;
            mx = fmaxf(mx, v[u]);
        }
        #pragma unroll
        for (int off = 32; off; off >>= 1) mx = fmaxf(mx, __shfl_xor(mx, off));
        float s = 0.f;
        #pragma unroll
        for (int u = 0; u < 5; ++u) { v[u] = __expf(v[u] - mx); s += v[u]; }
        #pragma unroll
        for (int off = 32; off; off >>= 1) s += __shfl_xor(s, off);
        const float inv = 1.f / s;
        asm volatile("" ::: "memory");   // order f32 reads before u16 writes
        #pragma unroll
        for (int u = 0; u < 5; ++u) {
            const int jl = lane + 64 * u;
            if (jl < KW) prow[jl] = f2bf(v[u] * inv);
        }
        if (lane >= 16 && lane < 32) prow[256 + lane] = 0;       // pad 272..287
    }
    asm volatile("" ::: "memory");

    // ---- PV: 9 k-chunks of 32 x 4 d-tiles; P-frags amortized over d ----
    f32x4 o[4];
    #pragma unroll
    for (int dt = 0; dt < 4; ++dt) o[dt] = (f32x4){0.f, 0.f, 0.f, 0.f};
    const unsigned short* PbU = (const unsigned short*)Sc;
    #pragma unroll
    for (int c = 0; c < 5; ++c) {
        const int nkk = (c < 4) ? 2 : 1;
        #pragma unroll
        for (int kk = 0; kk < nkk; ++kk) {
            int j0 = kb + c * 64 + kk * 32 + lg * 8;
            j0 = j0 < 0 ? 0 : (j0 > SEQ - 8 ? SEQ - 8 : j0);   // P=0 off-range
            const short8 pf = *(const short8*)&PbU[lr * (SCS * 2) + c * 64 + kk * 32 + lg * 8];
            #pragma unroll
            for (int dt = 0; dt < 4; ++dt) {
                const short8 vf = *(const short8*)&vTg[(size_t)(dt * 16 + lr) * SEQ + j0];
                o[dt] = __builtin_amdgcn_mfma_f32_16x16x32_bf16(pf, vf, o[dt], 0, 0, 0);
            }
        }
    }

    #pragma unroll
    for (int dt = 0; dt < 4; ++dt)
        #pragma unroll
        for (int r = 0; r < 4; ++r)
            Yb[(size_t)(b * SEQ + i0 + lg * 4 + r) * EMB + h * DH + dt * 16 + lr] = f2bf(o[dt][r]);
}

// out = Yb(bf16) @ Wo(f32, inline cvt)^T + bo (unchanged from R11).
__global__ __launch_bounds__(256)
void gemm_out(const unsigned short* __restrict__ A, const float* __restrict__ B,
              const float* __restrict__ bias, float* __restrict__ C) {
    constexpr int BM = 64, BN = 64, BK = 64;
    __shared__ unsigned short As[2][BM * BK];
    __shared__ unsigned short Bs[2][BN * BK];
    const int bid = blockIdx.x;
    const int wg = (bid & 7) * 64 + (bid >> 3);      // XCD-local A panels
    const int bm = (wg >> 3) * BM, bn = (wg & 7) * BN;
    const int t = threadIdx.x, lane = t & 63, wid = t >> 6;
    const int wr = wid >> 1, wc = wid & 1;
    const int lr = lane & 15, lg = lane >> 4;

    f32x4 acc[2][2];
    #pragma unroll
    for (int m = 0; m < 2; ++m)
        #pragma unroll
        for (int n = 0; n < 2; ++n)
            acc[m][n] = (f32x4){0.f, 0.f, 0.f, 0.f};

    float4 rB[2][2];
    auto gloadA = [&](int kt, int buf) {
        #pragma unroll
        for (int off = 0; off < BM * BK; off += 2048) {
            const int e = off + t * 8, r = e >> 6, c4 = (e & 63) >> 3;
            const int gc = (c4 ^ (r & 7)) << 3;
            gload_lds16(A + (size_t)(bm + r) * EMB + kt + gc, &As[buf][e]);
        }
    };
    auto loadB = [&](int kt) {
        #pragma unroll
        for (int i = 0; i < 2; ++i) {
            const int c = t + 256 * i, r = c >> 3, c8 = c & 7;
            const float4* s = (const float4*)(B + (size_t)(bn + r) * DIM + kt + c8 * 8);
            rB[i][0] = s[0]; rB[i][1] = s[1];
        }
    };

    gloadA(0, 0);
    loadB(0);
    for (int it = 0; it < 8; ++it) {
        const int cur = it & 1;
        #pragma unroll
        for (int i = 0; i < 2; ++i) {
            const int c = t + 256 * i, r = c >> 3, c8 = c & 7;
            const uint4 pk = make_uint4(cvtpk(rB[i][0].x, rB[i][0].y), cvtpk(rB[i][0].z, rB[i][0].w),
                                        cvtpk(rB[i][1].x, rB[i][1].y), cvtpk(rB[i][1].z, rB[i][1].w));
            *(uint4*)&Bs[cur][r * 64 + ((c8 ^ (r & 7)) << 3)] = pk;
        }
        __syncthreads();
        if (it < 7) { gloadA((it + 1) * BK, cur ^ 1); loadB((it + 1) * BK); }

        short8 af[2][2], bf[2][2];
        #pragma unroll
        for (int kk = 0; kk < 2; ++kk) {
            #pragma unroll
            for (int m = 0; m < 2; ++m) {
                const int row = wr * 32 + m * 16 + lr;
                af[kk][m] = *(const short8*)&As[cur][row * BK + (((kk * 4 + lg) ^ (row & 7)) << 3)];
            }
            #pragma unroll
            for (int n = 0; n < 2; ++n) {
                const int row = wc * 32 + n * 16 + lr;
                bf[kk][n] = *(const short8*)&Bs[cur][row * BK + (((kk * 4 + lg) ^ (row & 7)) << 3)];
            }
        }
        #pragma unroll
        for (int kk = 0; kk < 2; ++kk)
            #pragma unroll
            for (int m = 0; m < 2; ++m)
                #pragma unroll
                for (int n = 0; n < 2; ++n)
                    acc[m][n] = __builtin_amdgcn_mfma_f32_16x16x32_bf16(af[kk][m], bf[kk][n], acc[m][n], 0, 0, 0);
    }

    const int orow = bm + wr * 32 + lg * 4;
    const int oc0 = bn + wc * 32 + lr;
    #pragma unroll
    for (int m = 0; m < 2; ++m)
        #pragma unroll
        for (int n = 0; n < 2; ++n) {
            const int col = oc0 + n * 16;
            const float bv = bias[col];
            #pragma unroll
            for (int r = 0; r < 4; ++r)
                C[(size_t)(orow + m * 16 + r) * EMB + col] = acc[m][n][r] + bv;
        }
}

extern "C" void kernel_launch(void* const* d_in, const int* in_sizes, int n_in,
                              void* d_out, int out_size, void* d_ws, size_t ws_size,
                              hipStream_t stream) {
    const float* x    = (const float*)d_in[0];
    const int*   pad  = (const int*)d_in[1];
    const float* Wqkv = (const float*)d_in[2];
    const float* bqkv = (const float*)d_in[3];
    const float* Wo   = (const float*)d_in[4];
    const float* bo   = (const float*)d_in[5];
    float* out = (float*)d_out;

    char* p = (char*)d_ws;
    unsigned short* qkvh = (unsigned short*)p;                   // 12.6 MB (Q,K planes)
    unsigned short* vT   = (unsigned short*)(p + 12582912);      // 4 MB
    unsigned short* Yb   = (unsigned short*)(p + 16777216);      // 4 MB

    dim3 blk(256);
    gemm_qkv<<<dim3(768), blk, 0, stream>>>(x, Wqkv, bqkv, qkvh, vT);
    attn_mfma<<<dim3(512), blk, 0, stream>>>(qkvh, vT, pad, Yb);
    gemm_out<<<dim3(512), blk, 0, stream>>>(Yb, Wo, bo, out);
}

// Round 13
// 58.856 us; speedup vs baseline: 1.0380x; 1.0380x over previous
//
#include <hip/hip_runtime.h>

#define NH   8
#define SEQ  2048
#define DIM  512
#define EMB  512
#define DH   64
#define HALF 128
#define QT   16
#define KW   272          // QT + 2*HALF
#define SCS  276          // Sc row stride (f32)

typedef __attribute__((ext_vector_type(8))) short short8;
typedef __attribute__((ext_vector_type(4))) float f32x4;

__device__ __forceinline__ unsigned short f2bf(float f) {
    unsigned int u = __float_as_uint(f);
    return (unsigned short)((u + 0x7fffu + ((u >> 16) & 1u)) >> 16);
}

// packed f32x2 -> bf16x2 (RNE)
__device__ __forceinline__ unsigned cvtpk(float lo, float hi) {
    unsigned r;
    asm("v_cvt_pk_bf16_f32 %0, %1, %2" : "=v"(r) : "v"(lo), "v"(hi));
    return r;
}

__device__ __forceinline__ void gload_lds16(const void* g, void* l) {
    __builtin_amdgcn_global_load_lds((__attribute__((address_space(1))) void*)g,
                                     (__attribute__((address_space(3))) void*)l,
                                     16, 0, 0);
}

// qkv projection, f32 inputs converted inline during staging.
// 128x128 tiles (2x A-reuse vs R10's 128x64), BK=64, 384 blocks, XCD-swizzled.
// Each 64-col half of the tile lies in exactly one (h, q/k/v) plane.
// Q,K -> qkvh[b][h][ty][s][d] packed; V -> vT[b][h][d][s] packed.
__global__ __launch_bounds__(256)
void gemm_qkv(const float* __restrict__ A, const float* __restrict__ B,
              const float* __restrict__ bias, unsigned short* __restrict__ qkvh,
              unsigned short* __restrict__ vT) {
    constexpr int BM = 128, BN = 128, BK = 64;
    __shared__ unsigned short SM[BM * BK + BN * BK];   // 32 KB
    unsigned short* As = SM;            // [128][64] swizzled
    unsigned short* Bs = SM + BM * BK;  // [128][64] swizzled
    const int bid = blockIdx.x;
    const int wg = (bid & 7) * 48 + (bid >> 3);      // XCD-local panels
    const int bm = (wg / 12) * BM, bn = (wg % 12) * BN;
    const int t = threadIdx.x, lane = t & 63, wid = t >> 6;
    const int wr = wid >> 1, wc = wid & 1;
    const int lr = lane & 15, lg = lane >> 4;

    f32x4 acc[4][4];
    #pragma unroll
    for (int m = 0; m < 4; ++m)
        #pragma unroll
        for (int n = 0; n < 4; ++n)
            acc[m][n] = (f32x4){0.f, 0.f, 0.f, 0.f};

    for (int kt = 0; kt < DIM; kt += BK) {
        // stage A,B: linear f32 reads, cvt_pk, swizzled b128 LDS writes
        #pragma unroll
        for (int i = 0; i < 4; ++i) {
            const int c = t + 256 * i, r = c >> 3, c8 = c & 7;
            const float4* s = (const float4*)(A + (size_t)(bm + r) * DIM + kt + c8 * 8);
            const float4 v0 = s[0], v1 = s[1];
            const uint4 pk = make_uint4(cvtpk(v0.x, v0.y), cvtpk(v0.z, v0.w),
                                        cvtpk(v1.x, v1.y), cvtpk(v1.z, v1.w));
            *(uint4*)&As[r * 64 + ((c8 ^ (r & 7)) << 3)] = pk;
        }
        #pragma unroll
        for (int i = 0; i < 4; ++i) {
            const int c = t + 256 * i, r = c >> 3, c8 = c & 7;
            const float4* s = (const float4*)(B + (size_t)(bn + r) * DIM + kt + c8 * 8);
            const float4 v0 = s[0], v1 = s[1];
            const uint4 pk = make_uint4(cvtpk(v0.x, v0.y), cvtpk(v0.z, v0.w),
                                        cvtpk(v1.x, v1.y), cvtpk(v1.z, v1.w));
            *(uint4*)&Bs[r * 64 + ((c8 ^ (r & 7)) << 3)] = pk;
        }
        __syncthreads();
        short8 af[2][4], bf[2][4];
        #pragma unroll
        for (int kk = 0; kk < 2; ++kk) {
            #pragma unroll
            for (int m = 0; m < 4; ++m) {
                const int row = wr * 64 + m * 16 + lr;
                af[kk][m] = *(const short8*)&As[row * 64 + (((kk * 4 + lg) ^ (row & 7)) << 3)];
            }
            #pragma unroll
            for (int n = 0; n < 4; ++n) {
                const int row = wc * 64 + n * 16 + lr;
                bf[kk][n] = *(const short8*)&Bs[row * 64 + (((kk * 4 + lg) ^ (row & 7)) << 3)];
            }
        }
        #pragma unroll
        for (int kk = 0; kk < 2; ++kk)
            #pragma unroll
            for (int m = 0; m < 4; ++m)
                #pragma unroll
                for (int n = 0; n < 4; ++n)
                    acc[m][n] = __builtin_amdgcn_mfma_f32_16x16x32_bf16(af[kk][m], bf[kk][n], acc[m][n], 0, 0, 0);
        __syncthreads();
    }

    // epilogue: per 64-col half -> Tr[128][72] bf16 (reuse SM), packed stores
    unsigned short* Tr = SM;   // 18 KB < 32 KB pool
    const int bb = bm >> 11, s0 = bm & 2047;
    #pragma unroll
    for (int ch = 0; ch < 2; ++ch) {
        if (wc == ch) {
            #pragma unroll
            for (int n = 0; n < 4; ++n) {
                const int cl = n * 16 + lr;
                const float bv = bias[bn + ch * 64 + cl];
                #pragma unroll
                for (int m = 0; m < 4; ++m)
                    #pragma unroll
                    for (int r = 0; r < 4; ++r)
                        Tr[(wr * 64 + m * 16 + lg * 4 + r) * 72 + cl] = f2bf(acc[m][n][r] + bv);
            }
        }
        __syncthreads();
        const int colbase = bn + ch * 64;
        const int h = colbase / 192, ty = (colbase >> 6) % 3;
        if (ty < 2) {   // Q,K: contiguous [s][d] rows
            unsigned short* plane = qkvh + (((size_t)(bb * NH + h) * 3 + ty) * SEQ) * DH;
            const int s = t >> 1, hf = (t & 1) * 32;
            unsigned short* dst = plane + (size_t)(s0 + s) * DH + hf;
            #pragma unroll
            for (int k8 = 0; k8 < 4; ++k8)
                *(short8*)&dst[k8 * 8] = *(const short8*)&Tr[s * 72 + hf + k8 * 8];
        } else {        // V: transposed packed [d][s] stores
            const int d = t >> 2, pp = t & 3;
            unsigned short* vrow = vT + ((size_t)(bb * NH + h) * DH + d) * SEQ + s0 + pp * 32;
            #pragma unroll
            for (int k8 = 0; k8 < 4; ++k8) {
                alignas(16) unsigned short tmp[8];
                #pragma unroll
                for (int k = 0; k < 8; ++k) tmp[k] = Tr[(pp * 32 + k8 * 8 + k) * 72 + d];
                *(short8*)&vrow[k8 * 8] = *(short8*)tmp;
            }
        }
        __syncthreads();
    }
}

// MFMA windowed attention, LDS-minimal (the proven R10 version, QT=16,
// 2048 blocks, XCD-swizzled).
__global__ __launch_bounds__(256)
void attn_mfma(const unsigned short* __restrict__ qkvh,
               const unsigned short* __restrict__ vT,
               const int* __restrict__ pad,
               unsigned short* __restrict__ Yb) {
    const int bid = blockIdx.x;
    const int wg = (bid & 7) * 256 + (bid >> 3);     // XCD-local K/V planes
    const int bh = wg >> 7, qt = wg & 127;
    const int b = bh >> 3, h = bh & 7;
    const int i0 = qt * QT, kb = i0 - HALF;
    const int t = threadIdx.x, lane = t & 63, w = t >> 6;
    const int lr = lane & 15, lg = lane >> 4;

    __shared__ float Sc[QT * SCS];

    const unsigned short* Qg = qkvh + ((size_t)bh * 3 + 0) * SEQ * DH;
    const unsigned short* Kg = qkvh + ((size_t)bh * 3 + 1) * SEQ * DH;
    const unsigned short* vTg = vT + (size_t)bh * DH * SEQ;
    const int* padb = pad + b * SEQ;

    short8 qf[2];
    #pragma unroll
    for (int kk = 0; kk < 2; ++kk)
        qf[kk] = *(const short8*)&Qg[(size_t)(i0 + lr) * DH + kk * 32 + lg * 8];

    const int k0 = w * 16;
    #pragma unroll
    for (int c = 0; c < 5; ++c) {
        const int nc = (c < 4) ? 64 : 16;
        if (k0 < nc) {
            const int jl = c * 64 + k0 + lr;
            const int j = kb + jl;
            const int jc = j < 0 ? 0 : (j > SEQ - 1 ? SEQ - 1 : j);
            const int kv = (j >= 0 && j < SEQ) ? padb[j] : 0;
            f32x4 a0 = (f32x4){0.f, 0.f, 0.f, 0.f};
            #pragma unroll
            for (int kk = 0; kk < 2; ++kk) {
                const short8 bfr = *(const short8*)&Kg[(size_t)jc * DH + kk * 32 + lg * 8];
                a0 = __builtin_amdgcn_mfma_f32_16x16x32_bf16(qf[kk], bfr, a0, 0, 0, 0);
            }
            #pragma unroll
            for (int r = 0; r < 4; ++r) {
                const int q0 = lg * 4 + r;
                const bool ok = kv && (jl >= q0) && (jl <= q0 + 2 * HALF);
                Sc[q0 * SCS + jl] = ok ? a0[r] * 0.125f : -1e30f;
            }
        }
    }
    __syncthreads();

    for (int r = w; r < QT; r += 4) {
        float* row = &Sc[r * SCS];
        unsigned short* prow = (unsigned short*)row;
        if (!padb[i0 + r]) {
            #pragma unroll
            for (int u = 0; u < 5; ++u) {
                const int jl = lane + 64 * u;
                if (jl < KW) prow[jl] = 0;
            }
            if (lane >= 16 && lane < 32) prow[256 + lane] = 0;
            continue;
        }
        float v[5];
        float mx = -1e30f;
        #pragma unroll
        for (int u = 0; u < 5; ++u) {
            const int jl = lane + 64 * u;
            v[u] = (jl < KW) ? row[jl] : -1e30f;
            mx = fmaxf(mx, v[u]);
        }
        #pragma unroll
        for (int off = 32; off; off >>= 1) mx = fmaxf(mx, __shfl_xor(mx, off));
        float s = 0.f;
        #pragma unroll
        for (int u = 0; u < 5; ++u) { v[u] = __expf(v[u] - mx); s += v[u]; }
        #pragma unroll
        for (int off = 32; off; off >>= 1) s += __shfl_xor(s, off);
        const float inv = 1.f / s;
        asm volatile("" ::: "memory");
        #pragma unroll
        for (int u = 0; u < 5; ++u) {
            const int jl = lane + 64 * u;
            if (jl < KW) prow[jl] = f2bf(v[u] * inv);
        }
        if (lane >= 16 && lane < 32) prow[256 + lane] = 0;
    }
    __syncthreads();

    f32x4 o0 = (f32x4){0.f, 0.f, 0.f, 0.f};
    const unsigned short* PbU = (const unsigned short*)Sc;
    const int d0 = w * 16 + lr;
    #pragma unroll
    for (int c = 0; c < 5; ++c) {
        const int nkk = (c < 4) ? 2 : 1;
        #pragma unroll
        for (int kk = 0; kk < nkk; ++kk) {
            int j0 = kb + c * 64 + kk * 32 + lg * 8;
            j0 = j0 < 0 ? 0 : (j0 > SEQ - 8 ? SEQ - 8 : j0);
            const short8 vf = *(const short8*)&vTg[(size_t)d0 * SEQ + j0];
            const short8 pf = *(const short8*)&PbU[lr * (SCS * 2) + c * 64 + kk * 32 + lg * 8];
            o0 = __builtin_amdgcn_mfma_f32_16x16x32_bf16(pf, vf, o0, 0, 0, 0);
        }
    }

    #pragma unroll
    for (int r = 0; r < 4; ++r)
        Yb[(size_t)(b * SEQ + i0 + lg * 4 + r) * EMB + h * DH + d0] = f2bf(o0[r]);
}

// out = Yb(bf16) @ Wo(f32, inline cvt)^T + bo. 64x64 tiles, 512 blocks
// (the proven R10 version).
__global__ __launch_bounds__(256)
void gemm_out(const unsigned short* __restrict__ A, const float* __restrict__ B,
              const float* __restrict__ bias, float* __restrict__ C) {
    constexpr int BM = 64, BN = 64, BK = 64;
    __shared__ unsigned short As[BM * BK];
    __shared__ unsigned short Bs[BN * BK];
    const int bid = blockIdx.x;
    const int wg = (bid & 7) * 64 + (bid >> 3);      // XCD-local A panels
    const int bm = (wg >> 3) * BM, bn = (wg & 7) * BN;
    const int t = threadIdx.x, lane = t & 63, wid = t >> 6;
    const int wr = wid >> 1, wc = wid & 1;
    const int lr = lane & 15, lg = lane >> 4;

    f32x4 acc[2][2];
    #pragma unroll
    for (int m = 0; m < 2; ++m)
        #pragma unroll
        for (int n = 0; n < 2; ++n)
            acc[m][n] = (f32x4){0.f, 0.f, 0.f, 0.f};

    for (int kt = 0; kt < DIM; kt += BK) {
        // A (bf16): global_load_lds with source pre-swizzle
        #pragma unroll
        for (int off = 0; off < BM * BK; off += 2048) {
            const int e = off + t * 8, r = e >> 6, c4 = (e & 63) >> 3;
            const int gc = (c4 ^ (r & 7)) << 3;
            gload_lds16(A + (size_t)(bm + r) * EMB + kt + gc, &As[e]);
        }
        // B (f32 Wo): reg-staged cvt_pk, swizzled LDS writes
        #pragma unroll
        for (int i = 0; i < 2; ++i) {
            const int c = t + 256 * i, r = c >> 3, c8 = c & 7;
            const float4* src = (const float4*)(B + (size_t)(bn + r) * DIM + kt + c8 * 8);
            const float4 v0 = src[0], v1 = src[1];
            const uint4 pk = make_uint4(cvtpk(v0.x, v0.y), cvtpk(v0.z, v0.w),
                                        cvtpk(v1.x, v1.y), cvtpk(v1.z, v1.w));
            *(uint4*)&Bs[r * 64 + ((c8 ^ (r & 7)) << 3)] = pk;
        }
        __syncthreads();
        short8 af[2][2], bf[2][2];
        #pragma unroll
        for (int kk = 0; kk < 2; ++kk) {
            #pragma unroll
            for (int m = 0; m < 2; ++m) {
                const int row = wr * 32 + m * 16 + lr;
                af[kk][m] = *(const short8*)&As[row * BK + (((kk * 4 + lg) ^ (row & 7)) << 3)];
            }
            #pragma unroll
            for (int n = 0; n < 2; ++n) {
                const int row = wc * 32 + n * 16 + lr;
                bf[kk][n] = *(const short8*)&Bs[row * BK + (((kk * 4 + lg) ^ (row & 7)) << 3)];
            }
        }
        #pragma unroll
        for (int kk = 0; kk < 2; ++kk)
            #pragma unroll
            for (int m = 0; m < 2; ++m)
                #pragma unroll
                for (int n = 0; n < 2; ++n)
                    acc[m][n] = __builtin_amdgcn_mfma_f32_16x16x32_bf16(af[kk][m], bf[kk][n], acc[m][n], 0, 0, 0);
        __syncthreads();
    }

    const int orow = bm + wr * 32 + lg * 4;
    const int oc0 = bn + wc * 32 + lr;
    #pragma unroll
    for (int m = 0; m < 2; ++m)
        #pragma unroll
        for (int n = 0; n < 2; ++n) {
            const int col = oc0 + n * 16;
            const float bv = bias[col];
            #pragma unroll
            for (int r = 0; r < 4; ++r)
                C[(size_t)(orow + m * 16 + r) * EMB + col] = acc[m][n][r] + bv;
        }
}

extern "C" void kernel_launch(void* const* d_in, const int* in_sizes, int n_in,
                              void* d_out, int out_size, void* d_ws, size_t ws_size,
                              hipStream_t stream) {
    const float* x    = (const float*)d_in[0];
    const int*   pad  = (const int*)d_in[1];
    const float* Wqkv = (const float*)d_in[2];
    const float* bqkv = (const float*)d_in[3];
    const float* Wo   = (const float*)d_in[4];
    const float* bo   = (const float*)d_in[5];
    float* out = (float*)d_out;

    char* p = (char*)d_ws;
    unsigned short* qkvh = (unsigned short*)p;                   // 12.6 MB (Q,K planes)
    unsigned short* vT   = (unsigned short*)(p + 12582912);      // 4 MB
    unsigned short* Yb   = (unsigned short*)(p + 16777216);      // 4 MB

    dim3 blk(256);
    gemm_qkv<<<dim3(384), blk, 0, stream>>>(x, Wqkv, bqkv, qkvh, vT);
    attn_mfma<<<dim3(2048), blk, 0, stream>>>(qkvh, vT, pad, Yb);
    gemm_out<<<dim3(512), blk, 0, stream>>>(Yb, Wo, bo, out);
}

// Round 14
// 56.567 us; speedup vs baseline: 1.0800x; 1.0405x over previous
//
#include <hip/hip_runtime.h>

#define NH   8
#define SEQ  2048
#define DIM  512
#define EMB  512
#define DH   64
#define HALF 128
#define QT   16
#define KW   272          // QT + 2*HALF
#define SCS  276          // Sc row stride (f32)

typedef __attribute__((ext_vector_type(8))) short short8;
typedef __attribute__((ext_vector_type(4))) float f32x4;

__device__ __forceinline__ unsigned short f2bf(float f) {
    unsigned int u = __float_as_uint(f);
    return (unsigned short)((u + 0x7fffu + ((u >> 16) & 1u)) >> 16);
}

// packed f32x2 -> bf16x2 (RNE)
__device__ __forceinline__ unsigned cvtpk(float lo, float hi) {
    unsigned r;
    asm("v_cvt_pk_bf16_f32 %0, %1, %2" : "=v"(r) : "v"(lo), "v"(hi));
    return r;
}

__device__ __forceinline__ void gload_lds16(const void* g, void* l) {
    __builtin_amdgcn_global_load_lds((__attribute__((address_space(1))) void*)g,
                                     (__attribute__((address_space(3))) void*)l,
                                     16, 0, 0);
}

// qkv projection, f32 inputs converted inline during staging (R10 version).
// 128x64 tiles, BK=64, 768 blocks, XCD-swizzled. Q,K -> qkvh[b][h][ty][s][d]
// packed; V -> vT[b][h][d][s] packed.
__global__ __launch_bounds__(256)
void gemm_qkv(const float* __restrict__ A, const float* __restrict__ B,
              const float* __restrict__ bias, unsigned short* __restrict__ qkvh,
              unsigned short* __restrict__ vT) {
    constexpr int BM = 128, BN = 64, BK = 64;
    __shared__ unsigned short As[BM * BK];   // [128][64] swizzled
    __shared__ unsigned short Bs[BN * BK];   // [64][64]  swizzled
    const int bid = blockIdx.x;
    const int wg = (bid & 7) * 96 + (bid >> 3);     // XCD-local A panels
    const int bm = (wg / 24) * BM, bn = (wg % 24) * BN;
    const int t = threadIdx.x, lane = t & 63, wid = t >> 6;
    const int wr = wid >> 1, wc = wid & 1;
    const int lr = lane & 15, lg = lane >> 4;

    f32x4 acc[4][2];
    #pragma unroll
    for (int m = 0; m < 4; ++m)
        #pragma unroll
        for (int n = 0; n < 2; ++n)
            acc[m][n] = (f32x4){0.f, 0.f, 0.f, 0.f};

    for (int kt = 0; kt < DIM; kt += BK) {
        // stage A: linear f32 reads, cvt_pk, swizzled b128 LDS writes
        #pragma unroll
        for (int i = 0; i < 4; ++i) {
            const int c = t + 256 * i, r = c >> 3, c8 = c & 7;
            const float4* src = (const float4*)(A + (size_t)(bm + r) * DIM + kt + c8 * 8);
            const float4 v0 = src[0], v1 = src[1];
            const uint4 pk = make_uint4(cvtpk(v0.x, v0.y), cvtpk(v0.z, v0.w),
                                        cvtpk(v1.x, v1.y), cvtpk(v1.z, v1.w));
            *(uint4*)&As[r * 64 + ((c8 ^ (r & 7)) << 3)] = pk;
        }
        #pragma unroll
        for (int i = 0; i < 2; ++i) {
            const int c = t + 256 * i, r = c >> 3, c8 = c & 7;
            const float4* src = (const float4*)(B + (size_t)(bn + r) * DIM + kt + c8 * 8);
            const float4 v0 = src[0], v1 = src[1];
            const uint4 pk = make_uint4(cvtpk(v0.x, v0.y), cvtpk(v0.z, v0.w),
                                        cvtpk(v1.x, v1.y), cvtpk(v1.z, v1.w));
            *(uint4*)&Bs[r * 64 + ((c8 ^ (r & 7)) << 3)] = pk;
        }
        __syncthreads();
        short8 af[2][4], bf[2][2];
        #pragma unroll
        for (int kk = 0; kk < 2; ++kk) {
            #pragma unroll
            for (int m = 0; m < 4; ++m) {
                const int row = wr * 64 + m * 16 + lr;
                af[kk][m] = *(const short8*)&As[row * 64 + (((kk * 4 + lg) ^ (row & 7)) << 3)];
            }
            #pragma unroll
            for (int n = 0; n < 2; ++n) {
                const int row = wc * 32 + n * 16 + lr;
                bf[kk][n] = *(const short8*)&Bs[row * 64 + (((kk * 4 + lg) ^ (row & 7)) << 3)];
            }
        }
        #pragma unroll
        for (int kk = 0; kk < 2; ++kk)
            #pragma unroll
            for (int m = 0; m < 4; ++m)
                #pragma unroll
                for (int n = 0; n < 2; ++n)
                    acc[m][n] = __builtin_amdgcn_mfma_f32_16x16x32_bf16(af[kk][m], bf[kk][n], acc[m][n], 0, 0, 0);
        __syncthreads();
    }

    // epilogue: acc -> Tr[128][72] bf16 (reuse As/Bs), then packed stores
    unsigned short* Tr = As;
    #pragma unroll
    for (int n = 0; n < 2; ++n) {
        const int cl = wc * 32 + n * 16 + lr;
        const float bv = bias[bn + cl];
        #pragma unroll
        for (int m = 0; m < 4; ++m)
            #pragma unroll
            for (int r = 0; r < 4; ++r)
                Tr[(wr * 64 + m * 16 + lg * 4 + r) * 72 + cl] = f2bf(acc[m][n][r] + bv);
    }
    __syncthreads();

    const int h = bn / 192, ty = (bn >> 6) % 3;
    const int bb = bm >> 11, s0 = bm & 2047;
    if (ty < 2) {   // Q,K: contiguous [s][d] rows
        unsigned short* plane = qkvh + (((size_t)(bb * NH + h) * 3 + ty) * SEQ) * DH;
        const int s = t >> 1, hf = (t & 1) * 32;
        unsigned short* dst = plane + (size_t)(s0 + s) * DH + hf;
        #pragma unroll
        for (int k8 = 0; k8 < 4; ++k8)
            *(short8*)&dst[k8 * 8] = *(const short8*)&Tr[s * 72 + hf + k8 * 8];
    } else {        // V: transposed packed [d][s] stores
        const int d = t >> 2, pp = t & 3;
        unsigned short* vrow = vT + ((size_t)(bb * NH + h) * DH + d) * SEQ + s0 + pp * 32;
        #pragma unroll
        for (int k8 = 0; k8 < 4; ++k8) {
            alignas(16) unsigned short tmp[8];
            #pragma unroll
            for (int k = 0; k < 8; ++k) tmp[k] = Tr[(pp * 32 + k8 * 8 + k) * 72 + d];
            *(short8*)&vrow[k8 * 8] = *(short8*)tmp;
        }
    }
}

// MFMA windowed attention, LDS-minimal (R10 version + T5 setprio).
__global__ __launch_bounds__(256)
void attn_mfma(const unsigned short* __restrict__ qkvh,
               const unsigned short* __restrict__ vT,
               const int* __restrict__ pad,
               unsigned short* __restrict__ Yb) {
    const int bid = blockIdx.x;
    const int wg = (bid & 7) * 256 + (bid >> 3);     // XCD-local K/V planes
    const int bh = wg >> 7, qt = wg & 127;
    const int b = bh >> 3, h = bh & 7;
    const int i0 = qt * QT, kb = i0 - HALF;
    const int t = threadIdx.x, lane = t & 63, w = t >> 6;
    const int lr = lane & 15, lg = lane >> 4;

    __shared__ float Sc[QT * SCS];

    const unsigned short* Qg = qkvh + ((size_t)bh * 3 + 0) * SEQ * DH;
    const unsigned short* Kg = qkvh + ((size_t)bh * 3 + 1) * SEQ * DH;
    const unsigned short* vTg = vT + (size_t)bh * DH * SEQ;
    const int* padb = pad + b * SEQ;

    short8 qf[2];
    #pragma unroll
    for (int kk = 0; kk < 2; ++kk)
        qf[kk] = *(const short8*)&Qg[(size_t)(i0 + lr) * DH + kk * 32 + lg * 8];

    const int k0 = w * 16;
    #pragma unroll
    for (int c = 0; c < 5; ++c) {
        const int nc = (c < 4) ? 64 : 16;
        if (k0 < nc) {
            const int jl = c * 64 + k0 + lr;
            const int j = kb + jl;
            const int jc = j < 0 ? 0 : (j > SEQ - 1 ? SEQ - 1 : j);
            const int kv = (j >= 0 && j < SEQ) ? padb[j] : 0;
            f32x4 a0 = (f32x4){0.f, 0.f, 0.f, 0.f};
            __builtin_amdgcn_s_setprio(1);
            #pragma unroll
            for (int kk = 0; kk < 2; ++kk) {
                const short8 bfr = *(const short8*)&Kg[(size_t)jc * DH + kk * 32 + lg * 8];
                a0 = __builtin_amdgcn_mfma_f32_16x16x32_bf16(qf[kk], bfr, a0, 0, 0, 0);
            }
            __builtin_amdgcn_s_setprio(0);
            #pragma unroll
            for (int r = 0; r < 4; ++r) {
                const int q0 = lg * 4 + r;
                const bool ok = kv && (jl >= q0) && (jl <= q0 + 2 * HALF);
                Sc[q0 * SCS + jl] = ok ? a0[r] * 0.125f : -1e30f;
            }
        }
    }
    __syncthreads();

    for (int r = w; r < QT; r += 4) {
        float* row = &Sc[r * SCS];
        unsigned short* prow = (unsigned short*)row;
        if (!padb[i0 + r]) {
            #pragma unroll
            for (int u = 0; u < 5; ++u) {
                const int jl = lane + 64 * u;
                if (jl < KW) prow[jl] = 0;
            }
            if (lane >= 16 && lane < 32) prow[256 + lane] = 0;
            continue;
        }
        float v[5];
        float mx = -1e30f;
        #pragma unroll
        for (int u = 0; u < 5; ++u) {
            const int jl = lane + 64 * u;
            v[u] = (jl < KW) ? row[jl] : -1e30f;
            mx = fmaxf(mx, v[u]);
        }
        #pragma unroll
        for (int off = 32; off; off >>= 1) mx = fmaxf(mx, __shfl_xor(mx, off));
        float s = 0.f;
        #pragma unroll
        for (int u = 0; u < 5; ++u) { v[u] = __expf(v[u] - mx); s += v[u]; }
        #pragma unroll
        for (int off = 32; off; off >>= 1) s += __shfl_xor(s, off);
        const float inv = 1.f / s;
        asm volatile("" ::: "memory");
        #pragma unroll
        for (int u = 0; u < 5; ++u) {
            const int jl = lane + 64 * u;
            if (jl < KW) prow[jl] = f2bf(v[u] * inv);
        }
        if (lane >= 16 && lane < 32) prow[256 + lane] = 0;
    }
    __syncthreads();

    f32x4 o0 = (f32x4){0.f, 0.f, 0.f, 0.f};
    const unsigned short* PbU = (const unsigned short*)Sc;
    const int d0 = w * 16 + lr;
    #pragma unroll
    for (int c = 0; c < 5; ++c) {
        const int nkk = (c < 4) ? 2 : 1;
        #pragma unroll
        for (int kk = 0; kk < nkk; ++kk) {
            int j0 = kb + c * 64 + kk * 32 + lg * 8;
            j0 = j0 < 0 ? 0 : (j0 > SEQ - 8 ? SEQ - 8 : j0);
            const short8 vf = *(const short8*)&vTg[(size_t)d0 * SEQ + j0];
            const short8 pf = *(const short8*)&PbU[lr * (SCS * 2) + c * 64 + kk * 32 + lg * 8];
            __builtin_amdgcn_s_setprio(1);
            o0 = __builtin_amdgcn_mfma_f32_16x16x32_bf16(pf, vf, o0, 0, 0, 0);
            __builtin_amdgcn_s_setprio(0);
        }
    }

    #pragma unroll
    for (int r = 0; r < 4; ++r)
        Yb[(size_t)(b * SEQ + i0 + lg * 4 + r) * EMB + h * DH + d0] = f2bf(o0[r]);
}

// out = Yb(bf16) @ Wo(f32, inline cvt)^T + bo. 64x64 tiles, 512 blocks
// (R10 version).
__global__ __launch_bounds__(256)
void gemm_out(const unsigned short* __restrict__ A, const float* __restrict__ B,
              const float* __restrict__ bias, float* __restrict__ C) {
    constexpr int BM = 64, BN = 64, BK = 64;
    __shared__ unsigned short As[BM * BK];
    __shared__ unsigned short Bs[BN * BK];
    const int bid = blockIdx.x;
    const int wg = (bid & 7) * 64 + (bid >> 3);      // XCD-local A panels
    const int bm = (wg >> 3) * BM, bn = (wg & 7) * BN;
    const int t = threadIdx.x, lane = t & 63, wid = t >> 6;
    const int wr = wid >> 1, wc = wid & 1;
    const int lr = lane & 15, lg = lane >> 4;

    f32x4 acc[2][2];
    #pragma unroll
    for (int m = 0; m < 2; ++m)
        #pragma unroll
        for (int n = 0; n < 2; ++n)
            acc[m][n] = (f32x4){0.f, 0.f, 0.f, 0.f};

    for (int kt = 0; kt < DIM; kt += BK) {
        // A (bf16): global_load_lds with source pre-swizzle
        #pragma unroll
        for (int off = 0; off < BM * BK; off += 2048) {
            const int e = off + t * 8, r = e >> 6, c4 = (e & 63) >> 3;
            const int gc = (c4 ^ (r & 7)) << 3;
            gload_lds16(A + (size_t)(bm + r) * EMB + kt + gc, &As[e]);
        }
        // B (f32 Wo): reg-staged cvt_pk, swizzled LDS writes
        #pragma unroll
        for (int i = 0; i < 2; ++i) {
            const int c = t + 256 * i, r = c >> 3, c8 = c & 7;
            const float4* src = (const float4*)(B + (size_t)(bn + r) * DIM + kt + c8 * 8);
            const float4 v0 = src[0], v1 = src[1];
            const uint4 pk = make_uint4(cvtpk(v0.x, v0.y), cvtpk(v0.z, v0.w),
                                        cvtpk(v1.x, v1.y), cvtpk(v1.z, v1.w));
            *(uint4*)&Bs[r * 64 + ((c8 ^ (r & 7)) << 3)] = pk;
        }
        __syncthreads();
        short8 af[2][2], bf[2][2];
        #pragma unroll
        for (int kk = 0; kk < 2; ++kk) {
            #pragma unroll
            for (int m = 0; m < 2; ++m) {
                const int row = wr * 32 + m * 16 + lr;
                af[kk][m] = *(const short8*)&As[row * BK + (((kk * 4 + lg) ^ (row & 7)) << 3)];
            }
            #pragma unroll
            for (int n = 0; n < 2; ++n) {
                const int row = wc * 32 + n * 16 + lr;
                bf[kk][n] = *(const short8*)&Bs[row * BK + (((kk * 4 + lg) ^ (row & 7)) << 3)];
            }
        }
        #pragma unroll
        for (int kk = 0; kk < 2; ++kk)
            #pragma unroll
            for (int m = 0; m < 2; ++m)
                #pragma unroll
                for (int n = 0; n < 2; ++n)
                    acc[m][n] = __builtin_amdgcn_mfma_f32_16x16x32_bf16(af[kk][m], bf[kk][n], acc[m][n], 0, 0, 0);
        __syncthreads();
    }

    const int orow = bm + wr * 32 + lg * 4;
    const int oc0 = bn + wc * 32 + lr;
    #pragma unroll
    for (int m = 0; m < 2; ++m)
        #pragma unroll
        for (int n = 0; n < 2; ++n) {
            const int col = oc0 + n * 16;
            const float bv = bias[col];
            #pragma unroll
            for (int r = 0; r < 4; ++r)
                C[(size_t)(orow + m * 16 + r) * EMB + col] = acc[m][n][r] + bv;
        }
}

extern "C" void kernel_launch(void* const* d_in, const int* in_sizes, int n_in,
                              void* d_out, int out_size, void* d_ws, size_t ws_size,
                              hipStream_t stream) {
    const float* x    = (const float*)d_in[0];
    const int*   pad  = (const int*)d_in[1];
    const float* Wqkv = (const float*)d_in[2];
    const float* bqkv = (const float*)d_in[3];
    const float* Wo   = (const float*)d_in[4];
    const float* bo   = (const float*)d_in[5];
    float* out = (float*)d_out;

    char* p = (char*)d_ws;
    unsigned short* qkvh = (unsigned short*)p;                   // 12.6 MB (Q,K planes)
    unsigned short* vT   = (unsigned short*)(p + 12582912);      // 4 MB
    unsigned short* Yb   = (unsigned short*)(p + 16777216);      // 4 MB

    dim3 blk(256);
    gemm_qkv<<<dim3(768), blk, 0, stream>>>(x, Wqkv, bqkv, qkvh, vT);
    attn_mfma<<<dim3(2048), blk, 0, stream>>>(qkvh, vT, pad, Yb);
    gemm_out<<<dim3(512), blk, 0, stream>>>(Yb, Wo, bo, out);
}

// Round 15
// 51.768 us; speedup vs baseline: 1.1801x; 1.0927x over previous
//
#include <hip/hip_runtime.h>

#define NH   8
#define SEQ  2048
#define DIM  512
#define EMB  512
#define DH   64
#define HALF 128
#define QT   32           // queries per attn block (2 halves of 16)
#define KW2  288          // QT + 2*HALF
#define SCS2 292          // Sc row stride (f32)

typedef __attribute__((ext_vector_type(8))) short short8;
typedef __attribute__((ext_vector_type(4))) float f32x4;

__device__ __forceinline__ unsigned short f2bf(float f) {
    unsigned int u = __float_as_uint(f);
    return (unsigned short)((u + 0x7fffu + ((u >> 16) & 1u)) >> 16);
}

// packed f32x2 -> bf16x2 (RNE)
__device__ __forceinline__ unsigned cvtpk(float lo, float hi) {
    unsigned r;
    asm("v_cvt_pk_bf16_f32 %0, %1, %2" : "=v"(r) : "v"(lo), "v"(hi));
    return r;
}

__device__ __forceinline__ void gload_lds16(const void* g, void* l) {
    __builtin_amdgcn_global_load_lds((__attribute__((address_space(1))) void*)g,
                                     (__attribute__((address_space(3))) void*)l,
                                     16, 0, 0);
}

// qkv projection, f32 inputs converted inline during staging (R10/R14 version).
// 128x64 tiles, BK=64, 768 blocks, XCD-swizzled. Q,K -> qkvh[b][h][ty][s][d]
// packed; V -> vT[b][h][d][s] packed.
__global__ __launch_bounds__(256)
void gemm_qkv(const float* __restrict__ A, const float* __restrict__ B,
              const float* __restrict__ bias, unsigned short* __restrict__ qkvh,
              unsigned short* __restrict__ vT) {
    constexpr int BM = 128, BN = 64, BK = 64;
    __shared__ unsigned short As[BM * BK];   // [128][64] swizzled
    __shared__ unsigned short Bs[BN * BK];   // [64][64]  swizzled
    const int bid = blockIdx.x;
    const int wg = (bid & 7) * 96 + (bid >> 3);     // XCD-local A panels
    const int bm = (wg / 24) * BM, bn = (wg % 24) * BN;
    const int t = threadIdx.x, lane = t & 63, wid = t >> 6;
    const int wr = wid >> 1, wc = wid & 1;
    const int lr = lane & 15, lg = lane >> 4;

    f32x4 acc[4][2];
    #pragma unroll
    for (int m = 0; m < 4; ++m)
        #pragma unroll
        for (int n = 0; n < 2; ++n)
            acc[m][n] = (f32x4){0.f, 0.f, 0.f, 0.f};

    for (int kt = 0; kt < DIM; kt += BK) {
        #pragma unroll
        for (int i = 0; i < 4; ++i) {
            const int c = t + 256 * i, r = c >> 3, c8 = c & 7;
            const float4* src = (const float4*)(A + (size_t)(bm + r) * DIM + kt + c8 * 8);
            const float4 v0 = src[0], v1 = src[1];
            const uint4 pk = make_uint4(cvtpk(v0.x, v0.y), cvtpk(v0.z, v0.w),
                                        cvtpk(v1.x, v1.y), cvtpk(v1.z, v1.w));
            *(uint4*)&As[r * 64 + ((c8 ^ (r & 7)) << 3)] = pk;
        }
        #pragma unroll
        for (int i = 0; i < 2; ++i) {
            const int c = t + 256 * i, r = c >> 3, c8 = c & 7;
            const float4* src = (const float4*)(B + (size_t)(bn + r) * DIM + kt + c8 * 8);
            const float4 v0 = src[0], v1 = src[1];
            const uint4 pk = make_uint4(cvtpk(v0.x, v0.y), cvtpk(v0.z, v0.w),
                                        cvtpk(v1.x, v1.y), cvtpk(v1.z, v1.w));
            *(uint4*)&Bs[r * 64 + ((c8 ^ (r & 7)) << 3)] = pk;
        }
        __syncthreads();
        short8 af[2][4], bf[2][2];
        #pragma unroll
        for (int kk = 0; kk < 2; ++kk) {
            #pragma unroll
            for (int m = 0; m < 4; ++m) {
                const int row = wr * 64 + m * 16 + lr;
                af[kk][m] = *(const short8*)&As[row * 64 + (((kk * 4 + lg) ^ (row & 7)) << 3)];
            }
            #pragma unroll
            for (int n = 0; n < 2; ++n) {
                const int row = wc * 32 + n * 16 + lr;
                bf[kk][n] = *(const short8*)&Bs[row * 64 + (((kk * 4 + lg) ^ (row & 7)) << 3)];
            }
        }
        #pragma unroll
        for (int kk = 0; kk < 2; ++kk)
            #pragma unroll
            for (int m = 0; m < 4; ++m)
                #pragma unroll
                for (int n = 0; n < 2; ++n)
                    acc[m][n] = __builtin_amdgcn_mfma_f32_16x16x32_bf16(af[kk][m], bf[kk][n], acc[m][n], 0, 0, 0);
        __syncthreads();
    }

    unsigned short* Tr = As;
    #pragma unroll
    for (int n = 0; n < 2; ++n) {
        const int cl = wc * 32 + n * 16 + lr;
        const float bv = bias[bn + cl];
        #pragma unroll
        for (int m = 0; m < 4; ++m)
            #pragma unroll
            for (int r = 0; r < 4; ++r)
                Tr[(wr * 64 + m * 16 + lg * 4 + r) * 72 + cl] = f2bf(acc[m][n][r] + bv);
    }
    __syncthreads();

    const int h = bn / 192, ty = (bn >> 6) % 3;
    const int bb = bm >> 11, s0 = bm & 2047;
    if (ty < 2) {   // Q,K: contiguous [s][d] rows
        unsigned short* plane = qkvh + (((size_t)(bb * NH + h) * 3 + ty) * SEQ) * DH;
        const int s = t >> 1, hf = (t & 1) * 32;
        unsigned short* dst = plane + (size_t)(s0 + s) * DH + hf;
        #pragma unroll
        for (int k8 = 0; k8 < 4; ++k8)
            *(short8*)&dst[k8 * 8] = *(const short8*)&Tr[s * 72 + hf + k8 * 8];
    } else {        // V: transposed packed [d][s] stores
        const int d = t >> 2, pp = t & 3;
        unsigned short* vrow = vT + ((size_t)(bb * NH + h) * DH + d) * SEQ + s0 + pp * 32;
        #pragma unroll
        for (int k8 = 0; k8 < 4; ++k8) {
            alignas(16) unsigned short tmp[8];
            #pragma unroll
            for (int k = 0; k < 8; ++k) tmp[k] = Tr[(pp * 32 + k8 * 8 + k) * 72 + d];
            *(short8*)&vrow[k8 * 8] = *(short8*)tmp;
        }
    }
}

// MFMA windowed attention, QT=32, destaged: each K/V fragment feeds BOTH
// 16-query halves (halves K/V L2 traffic vs QT=16). 1024 blocks, 4 waves,
// LDS = 37.4 KB (4 blocks/CU). 2 barriers.
__global__ __launch_bounds__(256)
void attn_mfma(const unsigned short* __restrict__ qkvh,
               const unsigned short* __restrict__ vT,
               const int* __restrict__ pad,
               unsigned short* __restrict__ Yb) {
    const int bid = blockIdx.x;
    const int wg = (bid & 7) * 128 + (bid >> 3);     // XCD-local K/V planes
    const int bh = wg >> 6, qt = wg & 63;
    const int b = bh >> 3, h = bh & 7;
    const int i0 = qt * QT, kb = i0 - HALF;
    const int t = threadIdx.x, lane = t & 63, w = t >> 6;
    const int lr = lane & 15, lg = lane >> 4;

    __shared__ float Sc[QT * SCS2];                  // 37376 B

    const unsigned short* Qg = qkvh + ((size_t)bh * 3 + 0) * SEQ * DH;
    const unsigned short* Kg = qkvh + ((size_t)bh * 3 + 1) * SEQ * DH;
    const unsigned short* vTg = vT + (size_t)bh * DH * SEQ;
    const int* padb = pad + b * SEQ;

    // Q fragments for both query halves
    short8 qf[2][2];
    #pragma unroll
    for (int half = 0; half < 2; ++half)
        #pragma unroll
        for (int kk = 0; kk < 2; ++kk)
            qf[half][kk] = *(const short8*)&Qg[(size_t)(i0 + half * 16 + lr) * DH + kk * 32 + lg * 8];

    // ---- scores: 18 key-tiles of 16, wave w does tiles w, w+4, ... ----
    for (int tile = w; tile < 18; tile += 4) {
        const int jl = tile * 16 + lr;
        const int j = kb + jl;
        const int jc = j < 0 ? 0 : (j > SEQ - 1 ? SEQ - 1 : j);
        const int kv = (j >= 0 && j < SEQ) ? padb[j] : 0;
        f32x4 a0 = (f32x4){0.f, 0.f, 0.f, 0.f};
        f32x4 a1 = (f32x4){0.f, 0.f, 0.f, 0.f};
        __builtin_amdgcn_s_setprio(1);
        #pragma unroll
        for (int kk = 0; kk < 2; ++kk) {
            const short8 bfr = *(const short8*)&Kg[(size_t)jc * DH + kk * 32 + lg * 8];
            a0 = __builtin_amdgcn_mfma_f32_16x16x32_bf16(qf[0][kk], bfr, a0, 0, 0, 0);
            a1 = __builtin_amdgcn_mfma_f32_16x16x32_bf16(qf[1][kk], bfr, a1, 0, 0, 0);
        }
        __builtin_amdgcn_s_setprio(0);
        #pragma unroll
        for (int r = 0; r < 4; ++r) {
            const int q0 = lg * 4 + r, q1 = 16 + q0;
            const bool ok0 = kv && (jl >= q0) && (jl <= q0 + 2 * HALF);
            const bool ok1 = kv && (jl >= q1) && (jl <= q1 + 2 * HALF);
            Sc[q0 * SCS2 + jl] = ok0 ? a0[r] * 0.125f : -1e30f;
            Sc[q1 * SCS2 + jl] = ok1 ? a1[r] * 0.125f : -1e30f;
        }
    }
    __syncthreads();

    // ---- softmax: 8 rows per wave; bf16 P written in place over Sc ----
    for (int r = w; r < QT; r += 4) {
        float* row = &Sc[r * SCS2];
        unsigned short* prow = (unsigned short*)row;
        if (!padb[i0 + r]) {
            #pragma unroll
            for (int u = 0; u < 5; ++u) {
                const int jl = lane + 64 * u;
                if (jl < KW2) prow[jl] = 0;
            }
            continue;
        }
        float v[5];
        float mx = -1e30f;
        #pragma unroll
        for (int u = 0; u < 5; ++u) {
            const int jl = lane + 64 * u;
            v[u] = (jl < KW2) ? row[jl] : -1e30f;
            mx = fmaxf(mx, v[u]);
        }
        #pragma unroll
        for (int off = 32; off; off >>= 1) mx = fmaxf(mx, __shfl_xor(mx, off));
        float s = 0.f;
        #pragma unroll
        for (int u = 0; u < 5; ++u) { v[u] = __expf(v[u] - mx); s += v[u]; }
        #pragma unroll
        for (int off = 32; off; off >>= 1) s += __shfl_xor(s, off);
        const float inv = 1.f / s;
        asm volatile("" ::: "memory");   // order f32 reads before u16 writes
        #pragma unroll
        for (int u = 0; u < 5; ++u) {
            const int jl = lane + 64 * u;
            if (jl < KW2) prow[jl] = f2bf(v[u] * inv);
        }
    }
    __syncthreads();

    // ---- PV: 9 key-chunks of 32; V fragment shared across both halves ----
    f32x4 o0 = (f32x4){0.f, 0.f, 0.f, 0.f};
    f32x4 o1 = (f32x4){0.f, 0.f, 0.f, 0.f};
    const unsigned short* PbU = (const unsigned short*)Sc;
    const int d0 = w * 16 + lr;
    #pragma unroll
    for (int c = 0; c < 9; ++c) {
        int j0 = kb + c * 32 + lg * 8;
        j0 = j0 < 0 ? 0 : (j0 > SEQ - 8 ? SEQ - 8 : j0);   // P=0 off-range
        const short8 vf  = *(const short8*)&vTg[(size_t)d0 * SEQ + j0];
        const short8 pf0 = *(const short8*)&PbU[lr * (SCS2 * 2) + c * 32 + lg * 8];
        const short8 pf1 = *(const short8*)&PbU[(16 + lr) * (SCS2 * 2) + c * 32 + lg * 8];
        __builtin_amdgcn_s_setprio(1);
        o0 = __builtin_amdgcn_mfma_f32_16x16x32_bf16(pf0, vf, o0, 0, 0, 0);
        o1 = __builtin_amdgcn_mfma_f32_16x16x32_bf16(pf1, vf, o1, 0, 0, 0);
        __builtin_amdgcn_s_setprio(0);
    }

    #pragma unroll
    for (int r = 0; r < 4; ++r) {
        Yb[(size_t)(b * SEQ + i0 + lg * 4 + r) * EMB + h * DH + d0]      = f2bf(o0[r]);
        Yb[(size_t)(b * SEQ + i0 + 16 + lg * 4 + r) * EMB + h * DH + d0] = f2bf(o1[r]);
    }
}

// out = Yb(bf16) @ Wo(f32, inline cvt)^T + bo. 64x64 tiles, 512 blocks
// (R10/R14 version).
__global__ __launch_bounds__(256)
void gemm_out(const unsigned short* __restrict__ A, const float* __restrict__ B,
              const float* __restrict__ bias, float* __restrict__ C) {
    constexpr int BM = 64, BN = 64, BK = 64;
    __shared__ unsigned short As[BM * BK];
    __shared__ unsigned short Bs[BN * BK];
    const int bid = blockIdx.x;
    const int wg = (bid & 7) * 64 + (bid >> 3);      // XCD-local A panels
    const int bm = (wg >> 3) * BM, bn = (wg & 7) * BN;
    const int t = threadIdx.x, lane = t & 63, wid = t >> 6;
    const int wr = wid >> 1, wc = wid & 1;
    const int lr = lane & 15, lg = lane >> 4;

    f32x4 acc[2][2];
    #pragma unroll
    for (int m = 0; m < 2; ++m)
        #pragma unroll
        for (int n = 0; n < 2; ++n)
            acc[m][n] = (f32x4){0.f, 0.f, 0.f, 0.f};

    for (int kt = 0; kt < DIM; kt += BK) {
        #pragma unroll
        for (int off = 0; off < BM * BK; off += 2048) {
            const int e = off + t * 8, r = e >> 6, c4 = (e & 63) >> 3;
            const int gc = (c4 ^ (r & 7)) << 3;
            gload_lds16(A + (size_t)(bm + r) * EMB + kt + gc, &As[e]);
        }
        #pragma unroll
        for (int i = 0; i < 2; ++i) {
            const int c = t + 256 * i, r = c >> 3, c8 = c & 7;
            const float4* src = (const float4*)(B + (size_t)(bn + r) * DIM + kt + c8 * 8);
            const float4 v0 = src[0], v1 = src[1];
            const uint4 pk = make_uint4(cvtpk(v0.x, v0.y), cvtpk(v0.z, v0.w),
                                        cvtpk(v1.x, v1.y), cvtpk(v1.z, v1.w));
            *(uint4*)&Bs[r * 64 + ((c8 ^ (r & 7)) << 3)] = pk;
        }
        __syncthreads();
        short8 af[2][2], bf[2][2];
        #pragma unroll
        for (int kk = 0; kk < 2; ++kk) {
            #pragma unroll
            for (int m = 0; m < 2; ++m) {
                const int row = wr * 32 + m * 16 + lr;
                af[kk][m] = *(const short8*)&As[row * BK + (((kk * 4 + lg) ^ (row & 7)) << 3)];
            }
            #pragma unroll
            for (int n = 0; n < 2; ++n) {
                const int row = wc * 32 + n * 16 + lr;
                bf[kk][n] = *(const short8*)&Bs[row * BK + (((kk * 4 + lg) ^ (row & 7)) << 3)];
            }
        }
        #pragma unroll
        for (int kk = 0; kk < 2; ++kk)
            #pragma unroll
            for (int m = 0; m < 2; ++m)
                #pragma unroll
                for (int n = 0; n < 2; ++n)
                    acc[m][n] = __builtin_amdgcn_mfma_f32_16x16x32_bf16(af[kk][m], bf[kk][n], acc[m][n], 0, 0, 0);
        __syncthreads();
    }

    const int orow = bm + wr * 32 + lg * 4;
    const int oc0 = bn + wc * 32 + lr;
    #pragma unroll
    for (int m = 0; m < 2; ++m)
        #pragma unroll
        for (int n = 0; n < 2; ++n) {
            const int col = oc0 + n * 16;
            const float bv = bias[col];
            #pragma unroll
            for (int r = 0; r < 4; ++r)
                C[(size_t)(orow + m * 16 + r) * EMB + col] = acc[m][n][r] + bv;
        }
}

extern "C" void kernel_launch(void* const* d_in, const int* in_sizes, int n_in,
                              void* d_out, int out_size, void* d_ws, size_t ws_size,
                              hipStream_t stream) {
    const float* x    = (const float*)d_in[0];
    const int*   pad  = (const int*)d_in[1];
    const float* Wqkv = (const float*)d_in[2];
    const float* bqkv = (const float*)d_in[3];
    const float* Wo   = (const float*)d_in[4];
    const float* bo   = (const float*)d_in[5];
    float* out = (float*)d_out;

    char* p = (char*)d_ws;
    unsigned short* qkvh = (unsigned short*)p;                   // 12.6 MB (Q,K planes)
    unsigned short* vT   = (unsigned short*)(p + 12582912);      // 4 MB
    unsigned short* Yb   = (unsigned short*)(p + 16777216);      // 4 MB

    dim3 blk(256);
    gemm_qkv<<<dim3(768), blk, 0, stream>>>(x, Wqkv, bqkv, qkvh, vT);
    attn_mfma<<<dim3(1024), blk, 0, stream>>>(qkvh, vT, pad, Yb);
    gemm_out<<<dim3(512), blk, 0, stream>>>(Yb, Wo, bo, out);
}

// Round 16
// 48.909 us; speedup vs baseline: 1.2491x; 1.0585x over previous
//
#include <hip/hip_runtime.h>

#define NH   8
#define SEQ  2048
#define DIM  512
#define EMB  512
#define DH   64
#define HALF 128
#define QT   32           // queries per attn block (2 halves of 16)
#define KW2  288          // QT + 2*HALF
#define SCS2 292          // Sc row stride (f32)

typedef __attribute__((ext_vector_type(8))) short short8;
typedef __attribute__((ext_vector_type(4))) float f32x4;

__device__ __forceinline__ unsigned short f2bf(float f) {
    unsigned int u = __float_as_uint(f);
    return (unsigned short)((u + 0x7fffu + ((u >> 16) & 1u)) >> 16);
}

__device__ __forceinline__ void gload_lds16(const void* g, void* l) {
    __builtin_amdgcn_global_load_lds((__attribute__((address_space(1))) void*)g,
                                     (__attribute__((address_space(3))) void*)l,
                                     16, 0, 0);
}

// one kernel converts x, Wqkv, Wo -> contiguous bf16 region (768 blocks)
__global__ __launch_bounds__(256)
void cvt_all(const float* __restrict__ x, const float* __restrict__ wqkv,
             const float* __restrict__ wo, unsigned short* __restrict__ out) {
    const int i = blockIdx.x * 256 + threadIdx.x;   // float4 index, grid exact
    const float* src;
    int base;
    if (i < 524288)      { src = x;    base = 0; }
    else if (i < 720896) { src = wqkv; base = 524288; }
    else                 { src = wo;   base = 720896; }
    float4 v = ((const float4*)src)[i - base];
    ((ushort4*)out)[i] = make_ushort4(f2bf(v.x), f2bf(v.y), f2bf(v.z), f2bf(v.w));
}

// qkv projection from bf16 inputs, pure global_load_lds staging (no VALU).
// 128x64 tiles, BK=64, 768 blocks, XCD-swizzled, source-pre-swizzled LDS.
// Q,K -> qkvh[b][h][ty][s][d] packed; V -> vT[b][h][d][s] packed.
__global__ __launch_bounds__(256)
void gemm_qkv(const unsigned short* __restrict__ A, const unsigned short* __restrict__ B,
              const float* __restrict__ bias, unsigned short* __restrict__ qkvh,
              unsigned short* __restrict__ vT) {
    constexpr int BM = 128, BN = 64, BK = 64;
    __shared__ unsigned short As[BM * BK];   // [128][64] swizzled
    __shared__ unsigned short Bs[BN * BK];   // [64][64]  swizzled
    const int bid = blockIdx.x;
    const int wg = (bid & 7) * 96 + (bid >> 3);     // XCD-local A panels
    const int bm = (wg / 24) * BM, bn = (wg % 24) * BN;
    const int t = threadIdx.x, lane = t & 63, wid = t >> 6;
    const int wr = wid >> 1, wc = wid & 1;
    const int lr = lane & 15, lg = lane >> 4;

    f32x4 acc[4][2];
    #pragma unroll
    for (int m = 0; m < 4; ++m)
        #pragma unroll
        for (int n = 0; n < 2; ++n)
            acc[m][n] = (f32x4){0.f, 0.f, 0.f, 0.f};

    for (int kt = 0; kt < DIM; kt += BK) {
        #pragma unroll
        for (int off = 0; off < BM * BK; off += 2048) {
            const int e = off + t * 8, r = e >> 6, c4 = (e & 63) >> 3;
            const int gc = (c4 ^ (r & 7)) << 3;
            gload_lds16(A + (size_t)(bm + r) * DIM + kt + gc, &As[e]);
        }
        #pragma unroll
        for (int off = 0; off < BN * BK; off += 2048) {
            const int e = off + t * 8, r = e >> 6, c4 = (e & 63) >> 3;
            const int gc = (c4 ^ (r & 7)) << 3;
            gload_lds16(B + (size_t)(bn + r) * DIM + kt + gc, &Bs[e]);
        }
        __syncthreads();
        short8 af[2][4], bf[2][2];
        #pragma unroll
        for (int kk = 0; kk < 2; ++kk) {
            #pragma unroll
            for (int m = 0; m < 4; ++m) {
                const int row = wr * 64 + m * 16 + lr;
                af[kk][m] = *(const short8*)&As[row * 64 + (((kk * 4 + lg) ^ (row & 7)) << 3)];
            }
            #pragma unroll
            for (int n = 0; n < 2; ++n) {
                const int row = wc * 32 + n * 16 + lr;
                bf[kk][n] = *(const short8*)&Bs[row * 64 + (((kk * 4 + lg) ^ (row & 7)) << 3)];
            }
        }
        #pragma unroll
        for (int kk = 0; kk < 2; ++kk)
            #pragma unroll
            for (int m = 0; m < 4; ++m)
                #pragma unroll
                for (int n = 0; n < 2; ++n)
                    acc[m][n] = __builtin_amdgcn_mfma_f32_16x16x32_bf16(af[kk][m], bf[kk][n], acc[m][n], 0, 0, 0);
        __syncthreads();
    }

    // epilogue: acc -> Tr[128][72] bf16 (reuse As/Bs), then packed stores
    unsigned short* Tr = As;
    #pragma unroll
    for (int n = 0; n < 2; ++n) {
        const int cl = wc * 32 + n * 16 + lr;
        const float bv = bias[bn + cl];
        #pragma unroll
        for (int m = 0; m < 4; ++m)
            #pragma unroll
            for (int r = 0; r < 4; ++r)
                Tr[(wr * 64 + m * 16 + lg * 4 + r) * 72 + cl] = f2bf(acc[m][n][r] + bv);
    }
    __syncthreads();

    const int h = bn / 192, ty = (bn >> 6) % 3;
    const int bb = bm >> 11, s0 = bm & 2047;
    if (ty < 2) {   // Q,K: contiguous [s][d] rows
        unsigned short* plane = qkvh + (((size_t)(bb * NH + h) * 3 + ty) * SEQ) * DH;
        const int s = t >> 1, hf = (t & 1) * 32;
        unsigned short* dst = plane + (size_t)(s0 + s) * DH + hf;
        #pragma unroll
        for (int k8 = 0; k8 < 4; ++k8)
            *(short8*)&dst[k8 * 8] = *(const short8*)&Tr[s * 72 + hf + k8 * 8];
    } else {        // V: transposed packed [d][s] stores
        const int d = t >> 2, pp = t & 3;
        unsigned short* vrow = vT + ((size_t)(bb * NH + h) * DH + d) * SEQ + s0 + pp * 32;
        #pragma unroll
        for (int k8 = 0; k8 < 4; ++k8) {
            alignas(16) unsigned short tmp[8];
            #pragma unroll
            for (int k = 0; k < 8; ++k) tmp[k] = Tr[(pp * 32 + k8 * 8 + k) * 72 + d];
            *(short8*)&vrow[k8 * 8] = *(short8*)tmp;
        }
    }
}

// MFMA windowed attention, QT=32, destaged (R15 exact).
__global__ __launch_bounds__(256)
void attn_mfma(const unsigned short* __restrict__ qkvh,
               const unsigned short* __restrict__ vT,
               const int* __restrict__ pad,
               unsigned short* __restrict__ Yb) {
    const int bid = blockIdx.x;
    const int wg = (bid & 7) * 128 + (bid >> 3);     // XCD-local K/V planes
    const int bh = wg >> 6, qt = wg & 63;
    const int b = bh >> 3, h = bh & 7;
    const int i0 = qt * QT, kb = i0 - HALF;
    const int t = threadIdx.x, lane = t & 63, w = t >> 6;
    const int lr = lane & 15, lg = lane >> 4;

    __shared__ float Sc[QT * SCS2];                  // 37376 B

    const unsigned short* Qg = qkvh + ((size_t)bh * 3 + 0) * SEQ * DH;
    const unsigned short* Kg = qkvh + ((size_t)bh * 3 + 1) * SEQ * DH;
    const unsigned short* vTg = vT + (size_t)bh * DH * SEQ;
    const int* padb = pad + b * SEQ;

    short8 qf[2][2];
    #pragma unroll
    for (int half = 0; half < 2; ++half)
        #pragma unroll
        for (int kk = 0; kk < 2; ++kk)
            qf[half][kk] = *(const short8*)&Qg[(size_t)(i0 + half * 16 + lr) * DH + kk * 32 + lg * 8];

    for (int tile = w; tile < 18; tile += 4) {
        const int jl = tile * 16 + lr;
        const int j = kb + jl;
        const int jc = j < 0 ? 0 : (j > SEQ - 1 ? SEQ - 1 : j);
        const int kv = (j >= 0 && j < SEQ) ? padb[j] : 0;
        f32x4 a0 = (f32x4){0.f, 0.f, 0.f, 0.f};
        f32x4 a1 = (f32x4){0.f, 0.f, 0.f, 0.f};
        __builtin_amdgcn_s_setprio(1);
        #pragma unroll
        for (int kk = 0; kk < 2; ++kk) {
            const short8 bfr = *(const short8*)&Kg[(size_t)jc * DH + kk * 32 + lg * 8];
            a0 = __builtin_amdgcn_mfma_f32_16x16x32_bf16(qf[0][kk], bfr, a0, 0, 0, 0);
            a1 = __builtin_amdgcn_mfma_f32_16x16x32_bf16(qf[1][kk], bfr, a1, 0, 0, 0);
        }
        __builtin_amdgcn_s_setprio(0);
        #pragma unroll
        for (int r = 0; r < 4; ++r) {
            const int q0 = lg * 4 + r, q1 = 16 + q0;
            const bool ok0 = kv && (jl >= q0) && (jl <= q0 + 2 * HALF);
            const bool ok1 = kv && (jl >= q1) && (jl <= q1 + 2 * HALF);
            Sc[q0 * SCS2 + jl] = ok0 ? a0[r] * 0.125f : -1e30f;
            Sc[q1 * SCS2 + jl] = ok1 ? a1[r] * 0.125f : -1e30f;
        }
    }
    __syncthreads();

    for (int r = w; r < QT; r += 4) {
        float* row = &Sc[r * SCS2];
        unsigned short* prow = (unsigned short*)row;
        if (!padb[i0 + r]) {
            #pragma unroll
            for (int u = 0; u < 5; ++u) {
                const int jl = lane + 64 * u;
                if (jl < KW2) prow[jl] = 0;
            }
            continue;
        }
        float v[5];
        float mx = -1e30f;
        #pragma unroll
        for (int u = 0; u < 5; ++u) {
            const int jl = lane + 64 * u;
            v[u] = (jl < KW2) ? row[jl] : -1e30f;
            mx = fmaxf(mx, v[u]);
        }
        #pragma unroll
        for (int off = 32; off; off >>= 1) mx = fmaxf(mx, __shfl_xor(mx, off));
        float s = 0.f;
        #pragma unroll
        for (int u = 0; u < 5; ++u) { v[u] = __expf(v[u] - mx); s += v[u]; }
        #pragma unroll
        for (int off = 32; off; off >>= 1) s += __shfl_xor(s, off);
        const float inv = 1.f / s;
        asm volatile("" ::: "memory");
        #pragma unroll
        for (int u = 0; u < 5; ++u) {
            const int jl = lane + 64 * u;
            if (jl < KW2) prow[jl] = f2bf(v[u] * inv);
        }
    }
    __syncthreads();

    f32x4 o0 = (f32x4){0.f, 0.f, 0.f, 0.f};
    f32x4 o1 = (f32x4){0.f, 0.f, 0.f, 0.f};
    const unsigned short* PbU = (const unsigned short*)Sc;
    const int d0 = w * 16 + lr;
    #pragma unroll
    for (int c = 0; c < 9; ++c) {
        int j0 = kb + c * 32 + lg * 8;
        j0 = j0 < 0 ? 0 : (j0 > SEQ - 8 ? SEQ - 8 : j0);
        const short8 vf  = *(const short8*)&vTg[(size_t)d0 * SEQ + j0];
        const short8 pf0 = *(const short8*)&PbU[lr * (SCS2 * 2) + c * 32 + lg * 8];
        const short8 pf1 = *(const short8*)&PbU[(16 + lr) * (SCS2 * 2) + c * 32 + lg * 8];
        __builtin_amdgcn_s_setprio(1);
        o0 = __builtin_amdgcn_mfma_f32_16x16x32_bf16(pf0, vf, o0, 0, 0, 0);
        o1 = __builtin_amdgcn_mfma_f32_16x16x32_bf16(pf1, vf, o1, 0, 0, 0);
        __builtin_amdgcn_s_setprio(0);
    }

    #pragma unroll
    for (int r = 0; r < 4; ++r) {
        Yb[(size_t)(b * SEQ + i0 + lg * 4 + r) * EMB + h * DH + d0]      = f2bf(o0[r]);
        Yb[(size_t)(b * SEQ + i0 + 16 + lg * 4 + r) * EMB + h * DH + d0] = f2bf(o1[r]);
    }
}

// out = Yb(bf16) @ Wo(bf16)^T + bo. 64x64 tiles, 512 blocks, pure gload_lds.
__global__ __launch_bounds__(256)
void gemm_out(const unsigned short* __restrict__ A, const unsigned short* __restrict__ B,
              const float* __restrict__ bias, float* __restrict__ C) {
    constexpr int BM = 64, BN = 64, BK = 64;
    __shared__ unsigned short As[BM * BK];
    __shared__ unsigned short Bs[BN * BK];
    const int bid = blockIdx.x;
    const int wg = (bid & 7) * 64 + (bid >> 3);      // XCD-local A panels
    const int bm = (wg >> 3) * BM, bn = (wg & 7) * BN;
    const int t = threadIdx.x, lane = t & 63, wid = t >> 6;
    const int wr = wid >> 1, wc = wid & 1;
    const int lr = lane & 15, lg = lane >> 4;

    f32x4 acc[2][2];
    #pragma unroll
    for (int m = 0; m < 2; ++m)
        #pragma unroll
        for (int n = 0; n < 2; ++n)
            acc[m][n] = (f32x4){0.f, 0.f, 0.f, 0.f};

    for (int kt = 0; kt < DIM; kt += BK) {
        #pragma unroll
        for (int off = 0; off < BM * BK; off += 2048) {
            const int e = off + t * 8, r = e >> 6, c4 = (e & 63) >> 3;
            const int gc = (c4 ^ (r & 7)) << 3;
            gload_lds16(A + (size_t)(bm + r) * EMB + kt + gc, &As[e]);
        }
        #pragma unroll
        for (int off = 0; off < BN * BK; off += 2048) {
            const int e = off + t * 8, r = e >> 6, c4 = (e & 63) >> 3;
            const int gc = (c4 ^ (r & 7)) << 3;
            gload_lds16(B + (size_t)(bn + r) * DIM + kt + gc, &Bs[e]);
        }
        __syncthreads();
        short8 af[2][2], bf[2][2];
        #pragma unroll
        for (int kk = 0; kk < 2; ++kk) {
            #pragma unroll
            for (int m = 0; m < 2; ++m) {
                const int row = wr * 32 + m * 16 + lr;
                af[kk][m] = *(const short8*)&As[row * BK + (((kk * 4 + lg) ^ (row & 7)) << 3)];
            }
            #pragma unroll
            for (int n = 0; n < 2; ++n) {
                const int row = wc * 32 + n * 16 + lr;
                bf[kk][n] = *(const short8*)&Bs[row * BK + (((kk * 4 + lg) ^ (row & 7)) << 3)];
            }
        }
        #pragma unroll
        for (int kk = 0; kk < 2; ++kk)
            #pragma unroll
            for (int m = 0; m < 2; ++m)
                #pragma unroll
                for (int n = 0; n < 2; ++n)
                    acc[m][n] = __builtin_amdgcn_mfma_f32_16x16x32_bf16(af[kk][m], bf[kk][n], acc[m][n], 0, 0, 0);
        __syncthreads();
    }

    const int orow = bm + wr * 32 + lg * 4;
    const int oc0 = bn + wc * 32 + lr;
    #pragma unroll
    for (int m = 0; m < 2; ++m)
        #pragma unroll
        for (int n = 0; n < 2; ++n) {
            const int col = oc0 + n * 16;
            const float bv = bias[col];
            #pragma unroll
            for (int r = 0; r < 4; ++r)
                C[(size_t)(orow + m * 16 + r) * EMB + col] = acc[m][n][r] + bv;
        }
}

extern "C" void kernel_launch(void* const* d_in, const int* in_sizes, int n_in,
                              void* d_out, int out_size, void* d_ws, size_t ws_size,
                              hipStream_t stream) {
    const float* x    = (const float*)d_in[0];
    const int*   pad  = (const int*)d_in[1];
    const float* Wqkv = (const float*)d_in[2];
    const float* bqkv = (const float*)d_in[3];
    const float* Wo   = (const float*)d_in[4];
    const float* bo   = (const float*)d_in[5];
    float* out = (float*)d_out;

    char* p = (char*)d_ws;
    unsigned short* qkvh  = (unsigned short*)p;                   // 12.6 MB (Q,K planes)
    unsigned short* vT    = (unsigned short*)(p + 12582912);      // 4 MB
    unsigned short* Yb    = (unsigned short*)(p + 16777216);      // 4 MB
    unsigned short* cvtb  = (unsigned short*)(p + 20971520);      // 6 MB: xb|wqkvb|wob
    unsigned short* xb    = cvtb;
    unsigned short* wqkvb = cvtb + 2097152;
    unsigned short* wob   = cvtb + 2883584;

    dim3 blk(256);
    cvt_all<<<dim3(3072), blk, 0, stream>>>(x, Wqkv, Wo, cvtb);
    gemm_qkv<<<dim3(768), blk, 0, stream>>>(xb, wqkvb, bqkv, qkvh, vT);
    attn_mfma<<<dim3(1024), blk, 0, stream>>>(qkvh, vT, pad, Yb);
    gemm_out<<<dim3(512), blk, 0, stream>>>(Yb, wob, bo, out);
}